// Round 1
// baseline (1344.695 us; speedup 1.0000x reference)
//
#include <hip/hip_runtime.h>
#include <hip/hip_bf16.h>

#define B_   64
#define P_   100
#define N_   1000
#define EMB_ 128
#define HEAD_ 8
#define QKV_ 16

// a = 1/(1+2^((100-1000)/50)) = 1/(1+2^-18), computed in double like the reference.
constexpr double kTwoPowNeg18 = 3.814697265625e-06; // 2^-18 exact
constexpr double kA_d = 1.0 / (1.0 + kTwoPowNeg18);

// ---------------------------------------------------------------------------
// Kernel 1: K = en @ Wk, V = en @ Wv   (rows = B*N = 64000, 128 cols)
// 8 rows per block, 128 threads (one per output column).
// ---------------------------------------------------------------------------
__global__ __launch_bounds__(128) void kv_proj(
    const float* __restrict__ en, const float* __restrict__ Wk,
    const float* __restrict__ Wv, float* __restrict__ K, float* __restrict__ V)
{
    __shared__ float e_s[8][128];
    const int j  = threadIdx.x;
    const int r0 = blockIdx.x * 8;

    #pragma unroll
    for (int r = 0; r < 8; ++r)
        e_s[r][j] = en[(size_t)(r0 + r) * 128 + j];
    __syncthreads();

    float ak[8], av[8];
    #pragma unroll
    for (int r = 0; r < 8; ++r) { ak[r] = 0.f; av[r] = 0.f; }

    for (int i = 0; i < 128; ++i) {
        const float wk = Wk[i * 128 + j];
        const float wv = Wv[i * 128 + j];
        #pragma unroll
        for (int r = 0; r < 8; ++r) {
            const float e = e_s[r][i];
            ak[r] = fmaf(e, wk, ak[r]);
            av[r] = fmaf(e, wv, av[r]);
        }
    }

    #pragma unroll
    for (int r = 0; r < 8; ++r) {
        K[(size_t)(r0 + r) * 128 + j] = ak[r];
        V[(size_t)(r0 + r) * 128 + j] = av[r];
    }
}

// ---------------------------------------------------------------------------
// Kernel 2: Q = [eln | load | time] @ Wq   (rows = B*P = 6400, Wq is 130x128)
// ---------------------------------------------------------------------------
__global__ __launch_bounds__(128) void q_proj(
    const float* __restrict__ eln, const float* __restrict__ load_,
    const float* __restrict__ time_, const float* __restrict__ Wq,
    float* __restrict__ Q)
{
    __shared__ float e_s[8][130];
    const int j  = threadIdx.x;
    const int r0 = blockIdx.x * 8;

    #pragma unroll
    for (int r = 0; r < 8; ++r) {
        const int row = r0 + r;
        e_s[r][j] = eln[(size_t)row * 128 + j];
        if (j == 0) {
            e_s[r][128] = load_[row];
            e_s[r][129] = time_[row];
        }
    }
    __syncthreads();

    float a[8];
    #pragma unroll
    for (int r = 0; r < 8; ++r) a[r] = 0.f;

    for (int i = 0; i < 130; ++i) {
        const float w = Wq[i * 128 + j];
        #pragma unroll
        for (int r = 0; r < 8; ++r)
            a[r] = fmaf(e_s[r][i], w, a[r]);
    }

    #pragma unroll
    for (int r = 0; r < 8; ++r)
        Q[(size_t)(r0 + r) * 128 + j] = a[r];
}

// ---------------------------------------------------------------------------
// Kernel 3: fused attention + Wc matvec + pointer scores + final softmax.
// One block per (b,p), 256 threads.
// ---------------------------------------------------------------------------
__global__ __launch_bounds__(256) void attn_ptr(
    const float* __restrict__ K, const float* __restrict__ V,
    const float* __restrict__ Q, const float* __restrict__ en,
    const float* __restrict__ Wc, const float* __restrict__ bc,
    const float* __restrict__ cur_dist, const float* __restrict__ ninf,
    const float* __restrict__ noise, float* __restrict__ probs)
{
    __shared__ float q_s[128];
    __shared__ float sc[8][1024];     // per-head scores / exp weights, then ptr scores in sc[0]
    __shared__ float oc[128];         // attention out (concat heads)
    __shared__ float mh[128];         // mh_atten_out row
    __shared__ float part[2][128];
    __shared__ float denom[8];
    __shared__ float red[4];
    __shared__ float bval[2];

    const int bp = blockIdx.x;
    const int b  = bp / P_;
    const int t  = threadIdx.x;

    const float* Kb = K  + (size_t)b * N_ * 128;
    const float* Vb = V  + (size_t)b * N_ * 128;
    const float* Eb = en + (size_t)b * N_ * 128;
    const float* qrow = Q + (size_t)bp * 128;
    const float* nf = ninf     + (size_t)bp * N_;
    const float* cd = cur_dist + (size_t)bp * N_;
    const float* nz = noise    + (size_t)bp * N_;

    if (t < 128) q_s[t] = qrow[t];
    __syncthreads();

    // ---- Phase 1: scores[h][n] = (q_h . k_h)/4 + ninf ----
    const float4* q4 = (const float4*)q_s;
    for (int n = t; n < N_; n += 256) {
        const float4* kr = (const float4*)(Kb + (size_t)n * 128);
        const float msk = nf[n];
        #pragma unroll
        for (int h = 0; h < 8; ++h) {
            const float4 k0 = kr[h * 4 + 0];
            const float4 k1 = kr[h * 4 + 1];
            const float4 k2 = kr[h * 4 + 2];
            const float4 k3 = kr[h * 4 + 3];
            const float4 qa = q4[h * 4 + 0];
            const float4 qb = q4[h * 4 + 1];
            const float4 qc = q4[h * 4 + 2];
            const float4 qd = q4[h * 4 + 3];
            float d = k0.x * qa.x + k0.y * qa.y + k0.z * qa.z + k0.w * qa.w
                    + k1.x * qb.x + k1.y * qb.y + k1.z * qb.z + k1.w * qb.w
                    + k2.x * qc.x + k2.y * qc.y + k2.z * qc.z + k2.w * qc.w
                    + k3.x * qd.x + k3.y * qd.y + k3.z * qd.z + k3.w * qd.w;
            sc[h][n] = d * 0.25f + msk;
        }
    }
    __syncthreads();

    // ---- Phase 2: per-head softmax stats (exp stored back, denom kept) ----
    {
        const int h = t >> 5, lane = t & 31;
        float m = -INFINITY;
        for (int n = lane; n < N_; n += 32) m = fmaxf(m, sc[h][n]);
        #pragma unroll
        for (int off = 16; off > 0; off >>= 1) m = fmaxf(m, __shfl_xor(m, off, 32));
        float s = 0.f;
        for (int n = lane; n < N_; n += 32) {
            const float e = expf(sc[h][n] - m);
            sc[h][n] = e;
            s += e;
        }
        #pragma unroll
        for (int off = 16; off > 0; off >>= 1) s += __shfl_xor(s, off, 32);
        if (lane == 0) denom[h] = s;
    }
    __syncthreads();

    // ---- Phase 3: out[h][d] = sum_n w[h][n] * v[n][h*16+d] ----
    {
        const int half = t >> 7, t2 = t & 127;
        const int h = t2 >> 4;
        const int n0 = half * 500;
        float acc = 0.f;
        for (int n = n0; n < n0 + 500; ++n)
            acc = fmaf(sc[h][n], Vb[(size_t)n * 128 + t2], acc);
        part[half][t2] = acc;
    }
    __syncthreads();
    if (t < 128) {
        const int h = t >> 4;
        oc[t] = (part[0][t] + part[1][t]) / denom[h];
    }
    __syncthreads();

    // ---- Phase 4: mh = oc @ Wc + bc ----
    if (t < 128) {
        float acc = bc[t];
        for (int i = 0; i < 128; ++i)
            acc = fmaf(oc[i], Wc[i * 128 + t], acc);
        mh[t] = acc;
    }
    __syncthreads();

    // ---- Phase 5: pointer scores + heuristic blend + clip + mask ----
    const float A  = (float)kA_d;
    const float Bc2 = (float)(1.0 - kA_d);
    const float4* m4 = (const float4*)mh;
    for (int n = t; n < N_; n += 256) {
        const float4* er = (const float4*)(Eb + (size_t)n * 128);
        float d = 0.f;
        #pragma unroll
        for (int i = 0; i < 32; ++i) {
            const float4 e4 = er[i];
            const float4 mm = m4[i];
            d += e4.x * mm.x + e4.y * mm.y + e4.z * mm.z + e4.w * mm.w;
        }
        const float s2 = d / 11.3137085f;              // / SQRT_EMB
        const float st = cd[n] + cd[n];
        const float rh = -logf(st + 1e-6f);
        const float s  = s2 + A * rh + Bc2 * nz[n];
        const float cl = 10.f * tanhf(s);
        sc[0][n] = cl + nf[n];
    }
    __syncthreads();

    // ---- Phase 6: softmax over n, write probs ----
    {
        float m = -INFINITY;
        for (int n = t; n < N_; n += 256) m = fmaxf(m, sc[0][n]);
        #pragma unroll
        for (int off = 32; off > 0; off >>= 1) m = fmaxf(m, __shfl_xor(m, off, 64));
        if ((t & 63) == 0) red[t >> 6] = m;
        __syncthreads();
        if (t == 0) bval[0] = fmaxf(fmaxf(red[0], red[1]), fmaxf(red[2], red[3]));
        __syncthreads();
        const float bmax = bval[0];

        float s = 0.f;
        for (int n = t; n < N_; n += 256) {
            const float e = expf(sc[0][n] - bmax);
            sc[0][n] = e;
            s += e;
        }
        #pragma unroll
        for (int off = 32; off > 0; off >>= 1) s += __shfl_xor(s, off, 64);
        if ((t & 63) == 0) red[t >> 6] = s;
        __syncthreads();
        if (t == 0) bval[1] = red[0] + red[1] + red[2] + red[3];
        __syncthreads();

        const float inv = 1.f / bval[1];
        float* out = probs + (size_t)bp * N_;
        for (int n = t; n < N_; n += 256) out[n] = sc[0][n] * inv;
    }
}

// ---------------------------------------------------------------------------
extern "C" void kernel_launch(void* const* d_in, const int* in_sizes, int n_in,
                              void* d_out, int out_size, void* d_ws, size_t ws_size,
                              hipStream_t stream)
{
    const float* eln      = (const float*)d_in[0];
    const float* load_    = (const float*)d_in[1];
    const float* time_    = (const float*)d_in[2];
    const float* cur_dist = (const float*)d_in[3];
    const float* ninf     = (const float*)d_in[4];
    const float* noise    = (const float*)d_in[5];
    const float* en       = (const float*)d_in[6];
    const float* Wq       = (const float*)d_in[7];
    const float* Wk       = (const float*)d_in[8];
    const float* Wv       = (const float*)d_in[9];
    const float* Wc       = (const float*)d_in[10];
    const float* bc       = (const float*)d_in[11];
    float* probs = (float*)d_out;

    float* K = (float*)d_ws;                    // 64000*128 floats
    float* V = K + (size_t)B_ * N_ * 128;       // 64000*128 floats
    float* Q = V + (size_t)B_ * N_ * 128;       // 6400*128 floats

    kv_proj<<<(B_ * N_) / 8, 128, 0, stream>>>(en, Wk, Wv, K, V);
    q_proj<<<(B_ * P_) / 8, 128, 0, stream>>>(eln, load_, time_, Wq, Q);
    attn_ptr<<<B_ * P_, 256, 0, stream>>>(K, V, Q, en, Wc, bc,
                                          cur_dist, ninf, noise, probs);
}

// Round 3
// 641.222 us; speedup vs baseline: 2.0971x; 2.0971x over previous
//
#include <hip/hip_runtime.h>
#include <hip/hip_bf16.h>

#define B_   64
#define P_   100
#define N_   1000
#define EMB_ 128
#define HEAD_ 8
#define QKV_ 16
#define QT   4          // queries per block in attn kernel

constexpr double kTwoPowNeg18 = 3.814697265625e-06; // 2^-18 exact
constexpr double kA_d = 1.0 / (1.0 + kTwoPowNeg18);

// ---------------------------------------------------------------------------
// Kernel 1: K2/V2 = heads(en @ Wk/Wv) in [b][h][n][16] layout.
// 16 rows per block, 128 threads (one per output column h*16+d).
// ---------------------------------------------------------------------------
__global__ __launch_bounds__(128) void kv_proj(
    const float* __restrict__ en, const float* __restrict__ Wk,
    const float* __restrict__ Wv, float* __restrict__ K2, float* __restrict__ V2)
{
    __shared__ float e_s[16][128];
    const int j  = threadIdx.x;
    const int r0 = blockIdx.x * 16;

    #pragma unroll
    for (int r = 0; r < 16; ++r)
        e_s[r][j] = en[(size_t)(r0 + r) * 128 + j];
    __syncthreads();

    float ak[16], av[16];
    #pragma unroll
    for (int r = 0; r < 16; ++r) { ak[r] = 0.f; av[r] = 0.f; }

    for (int i = 0; i < 128; ++i) {
        const float wk = Wk[i * 128 + j];
        const float wv = Wv[i * 128 + j];
        #pragma unroll
        for (int r = 0; r < 16; ++r) {
            const float e = e_s[r][i];
            ak[r] = fmaf(e, wk, ak[r]);
            av[r] = fmaf(e, wv, av[r]);
        }
    }

    const int h = j >> 4, d = j & 15;
    #pragma unroll
    for (int r = 0; r < 16; ++r) {
        const int row = r0 + r;
        const int b = row / N_;
        const int n = row - b * N_;
        const size_t idx = ((size_t)(b * HEAD_ + h) * N_ + n) * 16 + d;
        K2[idx] = ak[r];
        V2[idx] = av[r];
    }
}

// ---------------------------------------------------------------------------
// Kernel 2: Q = [eln | load | time] @ Wq   (rows = B*P = 6400, Wq is 130x128)
// ---------------------------------------------------------------------------
__global__ __launch_bounds__(128) void q_proj(
    const float* __restrict__ eln, const float* __restrict__ load_,
    const float* __restrict__ time_, const float* __restrict__ Wq,
    float* __restrict__ Q)
{
    __shared__ float e_s[8][130];
    const int j  = threadIdx.x;
    const int r0 = blockIdx.x * 8;

    #pragma unroll
    for (int r = 0; r < 8; ++r) {
        const int row = r0 + r;
        e_s[r][j] = eln[(size_t)row * 128 + j];
        if (j == 0) {
            e_s[r][128] = load_[row];
            e_s[r][129] = time_[row];
        }
    }
    __syncthreads();

    float a[8];
    #pragma unroll
    for (int r = 0; r < 8; ++r) a[r] = 0.f;

    for (int i = 0; i < 130; ++i) {
        const float w = Wq[i * 128 + j];
        #pragma unroll
        for (int r = 0; r < 8; ++r)
            a[r] = fmaf(e_s[r][i], w, a[r]);
    }

    #pragma unroll
    for (int r = 0; r < 8; ++r)
        Q[(size_t)(r0 + r) * 128 + j] = a[r];
}

// ---------------------------------------------------------------------------
// Kernel 3: fused attention + Wc + pointer + final softmax, 4 queries/block.
// grid = B * P/QT = 1600 blocks, 256 threads (4 waves; wave w owns query w
// for the softmax/blend phases).
// ---------------------------------------------------------------------------
__global__ __launch_bounds__(256) void attn_ptr(
    const float* __restrict__ K2, const float* __restrict__ V2,
    const float* __restrict__ Q, const float* __restrict__ en,
    const float* __restrict__ Wc, const float* __restrict__ bc,
    const float* __restrict__ cur_dist, const float* __restrict__ ninf,
    const float* __restrict__ noise, float* __restrict__ probs)
{
    __shared__ float sc[QT][1008];     // scores / weights / ptr scores
    __shared__ float q_s[QT][128];
    __shared__ float out_s[QT][128];   // attention out (head-concat)
    __shared__ float mh_s[QT][128];    // mh_atten_out rows
    __shared__ float invden_s[QT];

    const int blk  = blockIdx.x;
    const int b    = blk / (P_ / QT);
    const int p0   = (blk % (P_ / QT)) * QT;
    const int bp0  = b * P_ + p0;
    const int t    = threadIdx.x;
    const int lane = t & 63;
    const int wv   = t >> 6;           // wave id = query id in per-wave phases

    for (int idx = t; idx < QT * 128; idx += 256)
        q_s[idx >> 7][idx & 127] = Q[(size_t)(bp0 + (idx >> 7)) * 128 + (idx & 127)];
    __syncthreads();

    const float* nf0 = ninf + (size_t)bp0 * N_;

    for (int h = 0; h < HEAD_; ++h) {
        // hoist this head's 4 query fragments into registers
        float qr[QT][16];
        #pragma unroll
        for (int q = 0; q < QT; ++q)
            #pragma unroll
            for (int i = 0; i < 16; ++i)
                qr[q][i] = q_s[q][h * 16 + i];

        // ---- scores ----
        const float* Kh = K2 + (size_t)(b * HEAD_ + h) * N_ * 16;
        for (int n = t; n < N_; n += 256) {
            const float4* kr = (const float4*)(Kh + (size_t)n * 16);
            const float4 k0 = kr[0], k1 = kr[1], k2 = kr[2], k3 = kr[3];
            #pragma unroll
            for (int q = 0; q < QT; ++q) {
                float d = k0.x * qr[q][0]  + k0.y * qr[q][1]
                        + k0.z * qr[q][2]  + k0.w * qr[q][3]
                        + k1.x * qr[q][4]  + k1.y * qr[q][5]
                        + k1.z * qr[q][6]  + k1.w * qr[q][7]
                        + k2.x * qr[q][8]  + k2.y * qr[q][9]
                        + k2.z * qr[q][10] + k2.w * qr[q][11]
                        + k3.x * qr[q][12] + k3.y * qr[q][13]
                        + k3.z * qr[q][14] + k3.w * qr[q][15];
                sc[q][n] = d * 0.25f + nf0[q * N_ + n];
            }
        }
        __syncthreads();

        // ---- per-query softmax (wave wv handles q = wv) ----
        {
            const int q = wv;
            float m = -INFINITY;
            for (int n = lane; n < N_; n += 64) m = fmaxf(m, sc[q][n]);
            #pragma unroll
            for (int off = 32; off > 0; off >>= 1) m = fmaxf(m, __shfl_xor(m, off));
            float s = 0.f;
            for (int n = lane; n < N_; n += 64) {
                const float e = expf(sc[q][n] - m);
                sc[q][n] = e;
                s += e;
            }
            #pragma unroll
            for (int off = 32; off > 0; off >>= 1) s += __shfl_xor(s, off);
            if (lane == 0) invden_s[q] = 1.f / s;
        }
        __syncthreads();

        // ---- PV: out[q][h*16+d] ----
        {
            const int q = wv, d = lane & 15, part = lane >> 4;
            const float* Vh = V2 + (size_t)(b * HEAD_ + h) * N_ * 16;
            float acc = 0.f;
            const int n0 = part * 250;
            for (int i = 0; i < 250; ++i) {
                const int n = n0 + i;
                acc = fmaf(sc[q][n], Vh[(size_t)n * 16 + d], acc);
            }
            acc += __shfl_xor(acc, 16);
            acc += __shfl_xor(acc, 32);
            if (lane < 16) out_s[q][h * 16 + d] = acc * invden_s[q];
        }
        __syncthreads();
    }

    // ---- mh = out @ Wc + bc (each thread: 2 queries, 1 column) ----
    {
        const int e = t & 127, qh = t >> 7;      // qh in {0,1} -> q = qh, qh+2
        float a0 = bc[e], a1 = a0;
        for (int i = 0; i < 128; ++i) {
            const float w = Wc[i * 128 + e];
            a0 = fmaf(out_s[qh][i], w, a0);
            a1 = fmaf(out_s[qh + 2][i], w, a1);
        }
        mh_s[qh][e] = a0;
        mh_s[qh + 2][e] = a1;
    }
    __syncthreads();

    // ---- pointer scores: sc[q][n] = mh[q] . en[n] ----
    const float* Eb = en + (size_t)b * N_ * 128;
    for (int n = t; n < N_; n += 256) {
        const float4* er = (const float4*)(Eb + (size_t)n * 128);
        const float4* m0 = (const float4*)mh_s[0];
        const float4* m1 = (const float4*)mh_s[1];
        const float4* m2 = (const float4*)mh_s[2];
        const float4* m3 = (const float4*)mh_s[3];
        float d0 = 0.f, d1 = 0.f, d2 = 0.f, d3 = 0.f;
        #pragma unroll 8
        for (int i = 0; i < 32; ++i) {
            const float4 e4 = er[i];
            const float4 a = m0[i], b4 = m1[i], c = m2[i], dd = m3[i];
            d0 += e4.x * a.x  + e4.y * a.y  + e4.z * a.z  + e4.w * a.w;
            d1 += e4.x * b4.x + e4.y * b4.y + e4.z * b4.z + e4.w * b4.w;
            d2 += e4.x * c.x  + e4.y * c.y  + e4.z * c.z  + e4.w * c.w;
            d3 += e4.x * dd.x + e4.y * dd.y + e4.z * dd.z + e4.w * dd.w;
        }
        sc[0][n] = d0; sc[1][n] = d1; sc[2][n] = d2; sc[3][n] = d3;
    }
    __syncthreads();

    // ---- blend + clip + mask + final softmax (wave wv -> query wv) ----
    {
        const int q  = wv;
        const int bp = bp0 + q;
        const float* cd = cur_dist + (size_t)bp * N_;
        const float* nz = noise    + (size_t)bp * N_;
        const float* nf = ninf     + (size_t)bp * N_;
        const float A   = (float)kA_d;
        const float Bc2 = (float)(1.0 - kA_d);

        float m = -INFINITY;
        for (int n = lane; n < N_; n += 64) {
            const float s2 = sc[q][n] / 11.3137085f;
            const float st = cd[n] + cd[n];
            const float rh = -logf(st + 1e-6f);
            const float s  = s2 + A * rh + Bc2 * nz[n];
            const float sm = 10.f * tanhf(s) + nf[n];
            sc[q][n] = sm;
            m = fmaxf(m, sm);
        }
        #pragma unroll
        for (int off = 32; off > 0; off >>= 1) m = fmaxf(m, __shfl_xor(m, off));

        float s = 0.f;
        for (int n = lane; n < N_; n += 64) {
            const float e = expf(sc[q][n] - m);
            sc[q][n] = e;
            s += e;
        }
        #pragma unroll
        for (int off = 32; off > 0; off >>= 1) s += __shfl_xor(s, off);

        const float inv = 1.f / s;
        float* out = probs + (size_t)bp * N_;
        for (int n = lane; n < N_; n += 64) out[n] = sc[q][n] * inv;
    }
}

// ---------------------------------------------------------------------------
extern "C" void kernel_launch(void* const* d_in, const int* in_sizes, int n_in,
                              void* d_out, int out_size, void* d_ws, size_t ws_size,
                              hipStream_t stream)
{
    const float* eln      = (const float*)d_in[0];
    const float* load_    = (const float*)d_in[1];
    const float* time_    = (const float*)d_in[2];
    const float* cur_dist = (const float*)d_in[3];
    const float* ninf     = (const float*)d_in[4];
    const float* noise    = (const float*)d_in[5];
    const float* en       = (const float*)d_in[6];
    const float* Wq       = (const float*)d_in[7];
    const float* Wk       = (const float*)d_in[8];
    const float* Wv       = (const float*)d_in[9];
    const float* Wc       = (const float*)d_in[10];
    const float* bc       = (const float*)d_in[11];
    float* probs = (float*)d_out;

    float* K2 = (float*)d_ws;                    // B*H*N*16 floats
    float* V2 = K2 + (size_t)B_ * HEAD_ * N_ * 16;
    float* Q  = V2 + (size_t)B_ * HEAD_ * N_ * 16;

    kv_proj<<<(B_ * N_) / 16, 128, 0, stream>>>(en, Wk, Wv, K2, V2);
    q_proj<<<(B_ * P_) / 8, 128, 0, stream>>>(eln, load_, time_, Wq, Q);
    attn_ptr<<<(B_ * P_) / QT, 256, 0, stream>>>(K2, V2, Q, en, Wc, bc,
                                                 cur_dist, ninf, noise, probs);
}

// Round 4
// 554.099 us; speedup vs baseline: 2.4268x; 1.1572x over previous
//
#include <hip/hip_runtime.h>
#include <hip/hip_bf16.h>

#define B_   64
#define P_   100
#define N_   1000
#define EMB_ 128
#define HEAD_ 8
#define QKV_ 16
#define QT   4          // queries per block in attn kernel

constexpr double kTwoPowNeg18 = 3.814697265625e-06; // 2^-18 exact
constexpr double kA_d = 1.0 / (1.0 + kTwoPowNeg18);

// ---------------------------------------------------------------------------
// Kernel 1: K2/V2 = heads(en @ Wk/Wv) in [b][h][n][16] layout.
// 32 rows per block, 256 threads (half = t>>7 picks rows 0-15 / 16-31).
// ---------------------------------------------------------------------------
__global__ __launch_bounds__(256) void kv_proj(
    const float* __restrict__ en, const float* __restrict__ Wk,
    const float* __restrict__ Wv, float* __restrict__ K2, float* __restrict__ V2)
{
    __shared__ __align__(16) float e_s[32][128];
    const int t = threadIdx.x;
    const int j = t & 127;
    const int half = t >> 7;
    const int r0 = blockIdx.x * 32;

    {
        const float4* src = (const float4*)(en + (size_t)r0 * 128);
        float4* dst = (float4*)&e_s[0][0];
        #pragma unroll
        for (int k = 0; k < 4; ++k) dst[t + 256 * k] = src[t + 256 * k];
    }
    __syncthreads();

    float ak[16], av[16];
    #pragma unroll
    for (int r = 0; r < 16; ++r) { ak[r] = 0.f; av[r] = 0.f; }

    const int rb = half * 16;
    for (int i = 0; i < 128; ++i) {
        const float wk = Wk[i * 128 + j];
        const float wv = Wv[i * 128 + j];
        #pragma unroll
        for (int r = 0; r < 16; ++r) {
            const float e = e_s[rb + r][i];
            ak[r] = fmaf(e, wk, ak[r]);
            av[r] = fmaf(e, wv, av[r]);
        }
    }

    const int h = j >> 4, d = j & 15;
    #pragma unroll
    for (int r = 0; r < 16; ++r) {
        const int row = r0 + rb + r;
        const int bb = row / N_;
        const int n = row - bb * N_;
        const size_t idx = ((size_t)(bb * HEAD_ + h) * N_ + n) * 16 + d;
        K2[idx] = ak[r];
        V2[idx] = av[r];
    }
}

// ---------------------------------------------------------------------------
// Kernel 2: Q = [eln | load | time] @ Wq   (rows = B*P = 6400, Wq is 130x128)
// ---------------------------------------------------------------------------
__global__ __launch_bounds__(128) void q_proj(
    const float* __restrict__ eln, const float* __restrict__ load_,
    const float* __restrict__ time_, const float* __restrict__ Wq,
    float* __restrict__ Q)
{
    __shared__ float e_s[8][130];
    const int j  = threadIdx.x;
    const int r0 = blockIdx.x * 8;

    #pragma unroll
    for (int r = 0; r < 8; ++r) {
        const int row = r0 + r;
        e_s[r][j] = eln[(size_t)row * 128 + j];
        if (j == 0) {
            e_s[r][128] = load_[row];
            e_s[r][129] = time_[row];
        }
    }
    __syncthreads();

    float a[8];
    #pragma unroll
    for (int r = 0; r < 8; ++r) a[r] = 0.f;

    for (int i = 0; i < 130; ++i) {
        const float w = Wq[i * 128 + j];
        #pragma unroll
        for (int r = 0; r < 8; ++r)
            a[r] = fmaf(e_s[r][i], w, a[r]);
    }

    #pragma unroll
    for (int r = 0; r < 8; ++r)
        Q[(size_t)(r0 + r) * 128 + j] = a[r];
}

// ---------------------------------------------------------------------------
// Kernel 3: fused attention + Wc + pointer + final softmax, 4 queries/block.
// grid = B * P/QT = 1600 blocks, 256 threads.
// PV: all 4 waves cooperate; lane (g=lane>>2, c=lane&3) loads one float4 of
// V and feeds all 4 queries (16 FMA / 16B); per-head partials go to LDS and
// a single finalize after the head loop produces out_s.
// ---------------------------------------------------------------------------
__global__ __launch_bounds__(256) void attn_ptr(
    const float* __restrict__ K2, const float* __restrict__ V2,
    const float* __restrict__ Q, const float* __restrict__ en,
    const float* __restrict__ Wc, const float* __restrict__ bc,
    const float* __restrict__ cur_dist, const float* __restrict__ ninf,
    const float* __restrict__ noise, float* __restrict__ probs)
{
    __shared__ __align__(16) float sc[QT][1008];      // scores / weights / ptr
    __shared__ __align__(16) float nf_s[QT][N_];      // staged ninf rows
    __shared__ __align__(16) float q_s[QT][128];
    __shared__ __align__(16) float out_s[QT][128];
    __shared__ __align__(16) float mh_s[QT][128];
    __shared__ __align__(16) float part_s[4][QT][HEAD_][16];
    __shared__ float invden_s[HEAD_][QT];

    const int blk  = blockIdx.x;
    const int b    = blk / (P_ / QT);
    const int p0   = (blk % (P_ / QT)) * QT;
    const int bp0  = b * P_ + p0;
    const int t    = threadIdx.x;
    const int lane = t & 63;
    const int wv   = t >> 6;

    // ---- stage q (512 floats) and ninf (4000 floats) ----
    {
        const float4* qsrc = (const float4*)(Q + (size_t)bp0 * 128);
        float4* qdst = (float4*)&q_s[0][0];
        if (t < 128) qdst[t] = qsrc[t];
        const float4* nsrc = (const float4*)(ninf + (size_t)bp0 * N_);
        float4* ndst = (float4*)&nf_s[0][0];
        for (int i = t; i < N_; i += 256) ndst[i] = nsrc[i];   // 1000 float4
    }
    __syncthreads();

    for (int h = 0; h < HEAD_; ++h) {
        // hoist this head's 4 query fragments into registers
        float qr[QT][16];
        #pragma unroll
        for (int q = 0; q < QT; ++q)
            #pragma unroll
            for (int i = 0; i < 16; ++i)
                qr[q][i] = q_s[q][h * 16 + i];

        // ---- scores ----
        const float* Kh = K2 + (size_t)(b * HEAD_ + h) * N_ * 16;
        for (int n = t; n < N_; n += 256) {
            const float4* kr = (const float4*)(Kh + (size_t)n * 16);
            const float4 k0 = kr[0], k1 = kr[1], k2 = kr[2], k3 = kr[3];
            #pragma unroll
            for (int q = 0; q < QT; ++q) {
                float d = k0.x * qr[q][0]  + k0.y * qr[q][1]
                        + k0.z * qr[q][2]  + k0.w * qr[q][3]
                        + k1.x * qr[q][4]  + k1.y * qr[q][5]
                        + k1.z * qr[q][6]  + k1.w * qr[q][7]
                        + k2.x * qr[q][8]  + k2.y * qr[q][9]
                        + k2.z * qr[q][10] + k2.w * qr[q][11]
                        + k3.x * qr[q][12] + k3.y * qr[q][13]
                        + k3.z * qr[q][14] + k3.w * qr[q][15];
                sc[q][n] = d * 0.25f + nf_s[q][n];
            }
        }
        __syncthreads();

        // ---- per-query softmax (wave wv handles q = wv) ----
        {
            const int q = wv;
            float m = -INFINITY;
            for (int n = lane; n < N_; n += 64) m = fmaxf(m, sc[q][n]);
            #pragma unroll
            for (int off = 32; off > 0; off >>= 1) m = fmaxf(m, __shfl_xor(m, off));
            float s = 0.f;
            for (int n = lane; n < N_; n += 64) {
                const float e = __expf(sc[q][n] - m);
                sc[q][n] = e;
                s += e;
            }
            #pragma unroll
            for (int off = 32; off > 0; off >>= 1) s += __shfl_xor(s, off);
            if (lane == 0) invden_s[h][q] = 1.f / s;
        }
        __syncthreads();

        // ---- PV: shared V loads, 16 FMA per float4 ----
        {
            const int c = lane & 3, g = lane >> 2;
            const float* Vh = V2 + (size_t)(b * HEAD_ + h) * N_ * 16 + 4 * c;
            const int n0 = wv * 250;
            float4 a0 = {0.f, 0.f, 0.f, 0.f}, a1 = a0, a2 = a0, a3 = a0;
            #pragma unroll 4
            for (int i = 0; i < 16; ++i) {
                const int nn = 16 * i + g;
                if (nn < 250) {
                    const int n = n0 + nn;
                    const float4 v4 = *(const float4*)(Vh + (size_t)n * 16);
                    const float w0 = sc[0][n], w1 = sc[1][n];
                    const float w2 = sc[2][n], w3 = sc[3][n];
                    a0.x = fmaf(w0, v4.x, a0.x); a0.y = fmaf(w0, v4.y, a0.y);
                    a0.z = fmaf(w0, v4.z, a0.z); a0.w = fmaf(w0, v4.w, a0.w);
                    a1.x = fmaf(w1, v4.x, a1.x); a1.y = fmaf(w1, v4.y, a1.y);
                    a1.z = fmaf(w1, v4.z, a1.z); a1.w = fmaf(w1, v4.w, a1.w);
                    a2.x = fmaf(w2, v4.x, a2.x); a2.y = fmaf(w2, v4.y, a2.y);
                    a2.z = fmaf(w2, v4.z, a2.z); a2.w = fmaf(w2, v4.w, a2.w);
                    a3.x = fmaf(w3, v4.x, a3.x); a3.y = fmaf(w3, v4.y, a3.y);
                    a3.z = fmaf(w3, v4.z, a3.z); a3.w = fmaf(w3, v4.w, a3.w);
                }
            }
            #pragma unroll
            for (int off = 4; off <= 32; off <<= 1) {
                a0.x += __shfl_xor(a0.x, off); a0.y += __shfl_xor(a0.y, off);
                a0.z += __shfl_xor(a0.z, off); a0.w += __shfl_xor(a0.w, off);
                a1.x += __shfl_xor(a1.x, off); a1.y += __shfl_xor(a1.y, off);
                a1.z += __shfl_xor(a1.z, off); a1.w += __shfl_xor(a1.w, off);
                a2.x += __shfl_xor(a2.x, off); a2.y += __shfl_xor(a2.y, off);
                a2.z += __shfl_xor(a2.z, off); a2.w += __shfl_xor(a2.w, off);
                a3.x += __shfl_xor(a3.x, off); a3.y += __shfl_xor(a3.y, off);
                a3.z += __shfl_xor(a3.z, off); a3.w += __shfl_xor(a3.w, off);
            }
            if (g == 0) {
                *(float4*)&part_s[wv][0][h][4 * c] = a0;
                *(float4*)&part_s[wv][1][h][4 * c] = a1;
                *(float4*)&part_s[wv][2][h][4 * c] = a2;
                *(float4*)&part_s[wv][3][h][4 * c] = a3;
            }
        }
        __syncthreads();
    }

    // ---- finalize: out_s[q][h*16+d] = sum_w part / denom ----
    for (int o = t; o < QT * HEAD_ * 16; o += 256) {
        const int q = o >> 7, rem = o & 127;
        const float s = (&part_s[0][q][0][0])[rem] + (&part_s[1][q][0][0])[rem]
                      + (&part_s[2][q][0][0])[rem] + (&part_s[3][q][0][0])[rem];
        out_s[q][rem] = s * invden_s[rem >> 4][q];
    }
    __syncthreads();

    // ---- mh = out @ Wc + bc (each thread: 2 queries, 1 column) ----
    {
        const int e = t & 127, qh = t >> 7;      // qh in {0,1} -> q = qh, qh+2
        float a0 = bc[e], a1 = a0;
        for (int i = 0; i < 128; ++i) {
            const float w = Wc[i * 128 + e];
            a0 = fmaf(out_s[qh][i], w, a0);
            a1 = fmaf(out_s[qh + 2][i], w, a1);
        }
        mh_s[qh][e] = a0;
        mh_s[qh + 2][e] = a1;
    }
    __syncthreads();

    // ---- pointer scores: sc[q][n] = mh[q] . en[n] ----
    const float* Eb = en + (size_t)b * N_ * 128;
    for (int n = t; n < N_; n += 256) {
        const float4* er = (const float4*)(Eb + (size_t)n * 128);
        const float4* m0 = (const float4*)mh_s[0];
        const float4* m1 = (const float4*)mh_s[1];
        const float4* m2 = (const float4*)mh_s[2];
        const float4* m3 = (const float4*)mh_s[3];
        float d0 = 0.f, d1 = 0.f, d2 = 0.f, d3 = 0.f;
        #pragma unroll 8
        for (int i = 0; i < 32; ++i) {
            const float4 e4 = er[i];
            const float4 a = m0[i], b4 = m1[i], c = m2[i], dd = m3[i];
            d0 += e4.x * a.x  + e4.y * a.y  + e4.z * a.z  + e4.w * a.w;
            d1 += e4.x * b4.x + e4.y * b4.y + e4.z * b4.z + e4.w * b4.w;
            d2 += e4.x * c.x  + e4.y * c.y  + e4.z * c.z  + e4.w * c.w;
            d3 += e4.x * dd.x + e4.y * dd.y + e4.z * dd.z + e4.w * dd.w;
        }
        sc[0][n] = d0; sc[1][n] = d1; sc[2][n] = d2; sc[3][n] = d3;
    }
    __syncthreads();

    // ---- blend + clip + mask + final softmax (wave wv -> query wv) ----
    {
        const int q  = wv;
        const int bp = bp0 + q;
        const float* cd = cur_dist + (size_t)bp * N_;
        const float* nz = noise    + (size_t)bp * N_;
        const float A   = (float)kA_d;
        const float Bc2 = (float)(1.0 - kA_d);

        float m = -INFINITY;
        for (int n = lane; n < N_; n += 64) {
            const float s2 = sc[q][n] / 11.3137085f;
            const float st = cd[n] + cd[n];
            const float rh = -logf(st + 1e-6f);
            const float s  = s2 + A * rh + Bc2 * nz[n];
            const float sm = 10.f * tanhf(s) + nf_s[q][n];
            sc[q][n] = sm;
            m = fmaxf(m, sm);
        }
        #pragma unroll
        for (int off = 32; off > 0; off >>= 1) m = fmaxf(m, __shfl_xor(m, off));

        float s = 0.f;
        for (int n = lane; n < N_; n += 64) {
            const float e = __expf(sc[q][n] - m);
            sc[q][n] = e;
            s += e;
        }
        #pragma unroll
        for (int off = 32; off > 0; off >>= 1) s += __shfl_xor(s, off);

        const float inv = 1.f / s;
        float* out = probs + (size_t)bp * N_;
        for (int n = lane; n < N_; n += 64) out[n] = sc[q][n] * inv;
    }
}

// ---------------------------------------------------------------------------
extern "C" void kernel_launch(void* const* d_in, const int* in_sizes, int n_in,
                              void* d_out, int out_size, void* d_ws, size_t ws_size,
                              hipStream_t stream)
{
    const float* eln      = (const float*)d_in[0];
    const float* load_    = (const float*)d_in[1];
    const float* time_    = (const float*)d_in[2];
    const float* cur_dist = (const float*)d_in[3];
    const float* ninf     = (const float*)d_in[4];
    const float* noise    = (const float*)d_in[5];
    const float* en       = (const float*)d_in[6];
    const float* Wq       = (const float*)d_in[7];
    const float* Wk       = (const float*)d_in[8];
    const float* Wv       = (const float*)d_in[9];
    const float* Wc       = (const float*)d_in[10];
    const float* bc       = (const float*)d_in[11];
    float* probs = (float*)d_out;

    float* K2 = (float*)d_ws;                    // B*H*N*16 floats
    float* V2 = K2 + (size_t)B_ * HEAD_ * N_ * 16;
    float* Q  = V2 + (size_t)B_ * HEAD_ * N_ * 16;

    kv_proj<<<(B_ * N_) / 32, 256, 0, stream>>>(en, Wk, Wv, K2, V2);
    q_proj<<<(B_ * P_) / 8, 128, 0, stream>>>(eln, load_, time_, Wq, Q);
    attn_ptr<<<(B_ * P_) / QT, 256, 0, stream>>>(K2, V2, Q, en, Wc, bc,
                                                 cur_dist, ninf, noise, probs);
}

// Round 5
// 549.457 us; speedup vs baseline: 2.4473x; 1.0084x over previous
//
#include <hip/hip_runtime.h>
#include <hip/hip_bf16.h>

#define B_   64
#define P_   100
#define N_   1000
#define EMB_ 128
#define HEAD_ 8
#define QKV_ 16
#define QT   4          // queries per tile

constexpr double kTwoPowNeg18 = 3.814697265625e-06; // 2^-18 exact
constexpr double kA_d = 1.0 / (1.0 + kTwoPowNeg18);

// ---------------------------------------------------------------------------
// Kernel 1: K2/V2 = heads(en @ Wk/Wv) in [b][h][n][16] layout.
// 32 rows per block, 256 threads. e-operand read as b128 broadcasts.
// ---------------------------------------------------------------------------
__global__ __launch_bounds__(256) void kv_proj(
    const float* __restrict__ en, const float* __restrict__ Wk,
    const float* __restrict__ Wv, float* __restrict__ K2, float* __restrict__ V2)
{
    __shared__ __align__(16) float e_s[32][128];
    const int t = threadIdx.x;
    const int j = t & 127;
    const int half = t >> 7;
    const int r0 = blockIdx.x * 32;

    {
        const float4* src = (const float4*)(en + (size_t)r0 * 128);
        float4* dst = (float4*)&e_s[0][0];
        #pragma unroll
        for (int k = 0; k < 4; ++k) dst[t + 256 * k] = src[t + 256 * k];
    }
    __syncthreads();

    float ak[16], av[16];
    #pragma unroll
    for (int r = 0; r < 16; ++r) { ak[r] = 0.f; av[r] = 0.f; }

    const int rb = half * 16;
    for (int i4 = 0; i4 < 32; ++i4) {
        float wk4[4], wv4[4];
        #pragma unroll
        for (int c = 0; c < 4; ++c) {
            wk4[c] = Wk[(4 * i4 + c) * 128 + j];
            wv4[c] = Wv[(4 * i4 + c) * 128 + j];
        }
        #pragma unroll
        for (int r = 0; r < 16; ++r) {
            const float4 e4 = *(const float4*)&e_s[rb + r][4 * i4];
            ak[r] = fmaf(e4.x, wk4[0], fmaf(e4.y, wk4[1],
                    fmaf(e4.z, wk4[2], fmaf(e4.w, wk4[3], ak[r]))));
            av[r] = fmaf(e4.x, wv4[0], fmaf(e4.y, wv4[1],
                    fmaf(e4.z, wv4[2], fmaf(e4.w, wv4[3], av[r]))));
        }
    }

    const int h = j >> 4, d = j & 15;
    #pragma unroll
    for (int r = 0; r < 16; ++r) {
        const int row = r0 + rb + r;
        const int bb = row / N_;
        const int n = row - bb * N_;
        const size_t idx = ((size_t)(bb * HEAD_ + h) * N_ + n) * 16 + d;
        K2[idx] = ak[r];
        V2[idx] = av[r];
    }
}

// ---------------------------------------------------------------------------
// Kernel 2: Q = [eln | load | time] @ Wq   (rows = B*P = 6400, Wq is 130x128)
// ---------------------------------------------------------------------------
__global__ __launch_bounds__(128) void q_proj(
    const float* __restrict__ eln, const float* __restrict__ load_,
    const float* __restrict__ time_, const float* __restrict__ Wq,
    float* __restrict__ Q)
{
    __shared__ __align__(16) float e_s[8][132];
    const int j  = threadIdx.x;
    const int r0 = blockIdx.x * 8;

    #pragma unroll
    for (int r = 0; r < 8; ++r) {
        const int row = r0 + r;
        e_s[r][j] = eln[(size_t)row * 128 + j];
        if (j == 0) {
            e_s[r][128] = load_[row];
            e_s[r][129] = time_[row];
        }
    }
    __syncthreads();

    float a[8];
    #pragma unroll
    for (int r = 0; r < 8; ++r) a[r] = 0.f;

    for (int i4 = 0; i4 < 32; ++i4) {
        float w4[4];
        #pragma unroll
        for (int c = 0; c < 4; ++c) w4[c] = Wq[(4 * i4 + c) * 128 + j];
        #pragma unroll
        for (int r = 0; r < 8; ++r) {
            const float4 e4 = *(const float4*)&e_s[r][4 * i4];
            a[r] = fmaf(e4.x, w4[0], fmaf(e4.y, w4[1],
                   fmaf(e4.z, w4[2], fmaf(e4.w, w4[3], a[r]))));
        }
    }
    #pragma unroll
    for (int i = 128; i < 130; ++i) {
        const float w = Wq[i * 128 + j];
        #pragma unroll
        for (int r = 0; r < 8; ++r)
            a[r] = fmaf(e_s[r][i], w, a[r]);
    }

    #pragma unroll
    for (int r = 0; r < 8; ++r)
        Q[(size_t)(r0 + r) * 128 + j] = a[r];
}

// ---------------------------------------------------------------------------
// Kernel 3a: per-head attention. grid = B * HEAD * (P/QT) = 12800 blocks.
// Block handles (b, h, 4 queries): scores -> softmax -> PV -> out_g chunk.
// ---------------------------------------------------------------------------
__global__ __launch_bounds__(256) void attn_heads(
    const float* __restrict__ K2, const float* __restrict__ V2,
    const float* __restrict__ Q, const float* __restrict__ ninf,
    float* __restrict__ out_g)
{
    __shared__ __align__(16) float sc[QT][1008];
    __shared__ __align__(16) float q_s[QT][16];
    __shared__ __align__(16) float part_s[4][QT][16];
    __shared__ float invden_s[QT];

    const int blk = blockIdx.x;
    const int b   = blk / (HEAD_ * 25);
    const int rem = blk - b * (HEAD_ * 25);
    const int h   = rem / 25;
    const int pt  = rem - h * 25;
    const int bp0 = b * P_ + pt * QT;
    const int t    = threadIdx.x;
    const int lane = t & 63;
    const int wv   = t >> 6;

    if (t < 64) q_s[t >> 4][t & 15] =
        Q[(size_t)(bp0 + (t >> 4)) * 128 + h * 16 + (t & 15)];
    __syncthreads();

    float qr[QT][16];
    #pragma unroll
    for (int q = 0; q < QT; ++q)
        #pragma unroll
        for (int c = 0; c < 4; ++c)
            *(float4*)&qr[q][4 * c] = *(const float4*)&q_s[q][4 * c];

    // hoist masks for this thread's n's into registers
    const float* nf0 = ninf + (size_t)bp0 * N_;
    float msk[QT][4];
    #pragma unroll
    for (int i = 0; i < 4; ++i) {
        const int n = t + 256 * i;
        if (n < N_) {
            #pragma unroll
            for (int q = 0; q < QT; ++q) msk[q][i] = nf0[q * N_ + n];
        }
    }

    // ---- scores ----
    const float* Kh = K2 + (size_t)(b * HEAD_ + h) * N_ * 16;
    #pragma unroll
    for (int i = 0; i < 4; ++i) {
        const int n = t + 256 * i;
        if (n < N_) {
            const float4* kr = (const float4*)(Kh + (size_t)n * 16);
            const float4 k0 = kr[0], k1 = kr[1], k2 = kr[2], k3 = kr[3];
            #pragma unroll
            for (int q = 0; q < QT; ++q) {
                float d = k0.x * qr[q][0]  + k0.y * qr[q][1]
                        + k0.z * qr[q][2]  + k0.w * qr[q][3]
                        + k1.x * qr[q][4]  + k1.y * qr[q][5]
                        + k1.z * qr[q][6]  + k1.w * qr[q][7]
                        + k2.x * qr[q][8]  + k2.y * qr[q][9]
                        + k2.z * qr[q][10] + k2.w * qr[q][11]
                        + k3.x * qr[q][12] + k3.y * qr[q][13]
                        + k3.z * qr[q][14] + k3.w * qr[q][15];
                sc[q][n] = d * 0.25f + msk[q][i];
            }
        }
    }
    __syncthreads();

    // ---- per-query softmax (wave wv -> query wv) ----
    {
        const int q = wv;
        float m = -INFINITY;
        for (int n = lane; n < N_; n += 64) m = fmaxf(m, sc[q][n]);
        #pragma unroll
        for (int off = 32; off > 0; off >>= 1) m = fmaxf(m, __shfl_xor(m, off));
        float s = 0.f;
        for (int n = lane; n < N_; n += 64) {
            const float e = __expf(sc[q][n] - m);
            sc[q][n] = e;
            s += e;
        }
        #pragma unroll
        for (int off = 32; off > 0; off >>= 1) s += __shfl_xor(s, off);
        if (lane == 0) invden_s[q] = 1.f / s;
    }
    __syncthreads();

    // ---- PV: shared V loads, 16 FMA per float4 ----
    {
        const int c = lane & 3, g = lane >> 2;
        const float* Vh = V2 + (size_t)(b * HEAD_ + h) * N_ * 16 + 4 * c;
        const int n0 = wv * 250;
        float4 a0 = {0.f, 0.f, 0.f, 0.f}, a1 = a0, a2 = a0, a3 = a0;
        #pragma unroll 4
        for (int i = 0; i < 16; ++i) {
            const int nn = 16 * i + g;
            if (nn < 250) {
                const int n = n0 + nn;
                const float4 v4 = *(const float4*)(Vh + (size_t)n * 16);
                const float w0 = sc[0][n], w1 = sc[1][n];
                const float w2 = sc[2][n], w3 = sc[3][n];
                a0.x = fmaf(w0, v4.x, a0.x); a0.y = fmaf(w0, v4.y, a0.y);
                a0.z = fmaf(w0, v4.z, a0.z); a0.w = fmaf(w0, v4.w, a0.w);
                a1.x = fmaf(w1, v4.x, a1.x); a1.y = fmaf(w1, v4.y, a1.y);
                a1.z = fmaf(w1, v4.z, a1.z); a1.w = fmaf(w1, v4.w, a1.w);
                a2.x = fmaf(w2, v4.x, a2.x); a2.y = fmaf(w2, v4.y, a2.y);
                a2.z = fmaf(w2, v4.z, a2.z); a2.w = fmaf(w2, v4.w, a2.w);
                a3.x = fmaf(w3, v4.x, a3.x); a3.y = fmaf(w3, v4.y, a3.y);
                a3.z = fmaf(w3, v4.z, a3.z); a3.w = fmaf(w3, v4.w, a3.w);
            }
        }
        #pragma unroll
        for (int off = 4; off <= 32; off <<= 1) {
            a0.x += __shfl_xor(a0.x, off); a0.y += __shfl_xor(a0.y, off);
            a0.z += __shfl_xor(a0.z, off); a0.w += __shfl_xor(a0.w, off);
            a1.x += __shfl_xor(a1.x, off); a1.y += __shfl_xor(a1.y, off);
            a1.z += __shfl_xor(a1.z, off); a1.w += __shfl_xor(a1.w, off);
            a2.x += __shfl_xor(a2.x, off); a2.y += __shfl_xor(a2.y, off);
            a2.z += __shfl_xor(a2.z, off); a2.w += __shfl_xor(a2.w, off);
            a3.x += __shfl_xor(a3.x, off); a3.y += __shfl_xor(a3.y, off);
            a3.z += __shfl_xor(a3.z, off); a3.w += __shfl_xor(a3.w, off);
        }
        if (g == 0) {
            *(float4*)&part_s[wv][0][4 * c] = a0;
            *(float4*)&part_s[wv][1][4 * c] = a1;
            *(float4*)&part_s[wv][2][4 * c] = a2;
            *(float4*)&part_s[wv][3][4 * c] = a3;
        }
    }
    __syncthreads();

    // ---- finalize: out_g[bp0+q][h*16+d] ----
    if (t < 64) {
        const int q = t >> 4, d = t & 15;
        const float s = part_s[0][q][d] + part_s[1][q][d]
                      + part_s[2][q][d] + part_s[3][q][d];
        out_g[(size_t)(bp0 + q) * 128 + h * 16 + d] = s * invden_s[q];
    }
}

// ---------------------------------------------------------------------------
// Kernel 3b: Wc matvec + pointer scores + blend + final softmax.
// grid = B * P/QT = 1600 blocks, 256 threads.
// ---------------------------------------------------------------------------
__global__ __launch_bounds__(256) void ptr_epilogue(
    const float* __restrict__ out_g, const float* __restrict__ en,
    const float* __restrict__ Wc, const float* __restrict__ bc,
    const float* __restrict__ cur_dist, const float* __restrict__ ninf,
    const float* __restrict__ noise, float* __restrict__ probs)
{
    __shared__ __align__(16) float sc[QT][1008];
    __shared__ __align__(16) float out_s[QT][128];
    __shared__ __align__(16) float mh_s[QT][128];

    const int blk  = blockIdx.x;
    const int b    = blk / 25;
    const int pt   = blk - b * 25;
    const int bp0  = b * P_ + pt * QT;
    const int t    = threadIdx.x;
    const int lane = t & 63;
    const int wv   = t >> 6;

    if (t < 128)
        ((float4*)&out_s[0][0])[t] = ((const float4*)(out_g + (size_t)bp0 * 128))[t];
    __syncthreads();

    // ---- mh = out @ Wc + bc (each thread: 2 queries, 1 column) ----
    {
        const int e = t & 127, qh = t >> 7;
        float a0 = bc[e], a1 = a0;
        for (int i = 0; i < 128; ++i) {
            const float w = Wc[i * 128 + e];
            a0 = fmaf(out_s[qh][i], w, a0);
            a1 = fmaf(out_s[qh + 2][i], w, a1);
        }
        mh_s[qh][e] = a0;
        mh_s[qh + 2][e] = a1;
    }
    __syncthreads();

    // ---- pointer scores, two n per mh read ----
    const float* Eb = en + (size_t)b * N_ * 128;
    const float4* m0 = (const float4*)mh_s[0];
    const float4* m1 = (const float4*)mh_s[1];
    const float4* m2 = (const float4*)mh_s[2];
    const float4* m3 = (const float4*)mh_s[3];
    #pragma unroll
    for (int half = 0; half < 2; ++half) {
        const int na = t + half * 512;          // < 768
        const int nb = na + 256;
        const bool vb = (nb < N_);
        const float4* ea = (const float4*)(Eb + (size_t)na * 128);
        const float4* eb = (const float4*)(Eb + (size_t)(vb ? nb : na) * 128);
        float d0a = 0.f, d1a = 0.f, d2a = 0.f, d3a = 0.f;
        float d0b = 0.f, d1b = 0.f, d2b = 0.f, d3b = 0.f;
        #pragma unroll 4
        for (int i = 0; i < 32; ++i) {
            const float4 A4 = m0[i], B4 = m1[i], C4 = m2[i], D4 = m3[i];
            const float4 e1 = ea[i];
            const float4 e2 = eb[i];
            d0a += e1.x * A4.x + e1.y * A4.y + e1.z * A4.z + e1.w * A4.w;
            d1a += e1.x * B4.x + e1.y * B4.y + e1.z * B4.z + e1.w * B4.w;
            d2a += e1.x * C4.x + e1.y * C4.y + e1.z * C4.z + e1.w * C4.w;
            d3a += e1.x * D4.x + e1.y * D4.y + e1.z * D4.z + e1.w * D4.w;
            d0b += e2.x * A4.x + e2.y * A4.y + e2.z * A4.z + e2.w * A4.w;
            d1b += e2.x * B4.x + e2.y * B4.y + e2.z * B4.z + e2.w * B4.w;
            d2b += e2.x * C4.x + e2.y * C4.y + e2.z * C4.z + e2.w * C4.w;
            d3b += e2.x * D4.x + e2.y * D4.y + e2.z * D4.z + e2.w * D4.w;
        }
        sc[0][na] = d0a; sc[1][na] = d1a; sc[2][na] = d2a; sc[3][na] = d3a;
        if (vb) { sc[0][nb] = d0b; sc[1][nb] = d1b; sc[2][nb] = d2b; sc[3][nb] = d3b; }
    }
    __syncthreads();

    // ---- blend + clip + mask + final softmax (wave wv -> query wv) ----
    {
        const int q  = wv;
        const int bp = bp0 + q;
        const float* cd = cur_dist + (size_t)bp * N_;
        const float* nz = noise    + (size_t)bp * N_;
        const float* nf = ninf     + (size_t)bp * N_;
        const float A   = (float)kA_d;
        const float Bc2 = (float)(1.0 - kA_d);

        float m = -INFINITY;
        for (int n = lane; n < N_; n += 64) {
            const float s2 = sc[q][n] / 11.3137085f;
            const float st = cd[n] + cd[n];
            const float rh = -logf(st + 1e-6f);
            const float s  = s2 + A * rh + Bc2 * nz[n];
            const float sm = 10.f * tanhf(s) + nf[n];
            sc[q][n] = sm;
            m = fmaxf(m, sm);
        }
        #pragma unroll
        for (int off = 32; off > 0; off >>= 1) m = fmaxf(m, __shfl_xor(m, off));

        float s = 0.f;
        for (int n = lane; n < N_; n += 64) {
            const float e = __expf(sc[q][n] - m);
            sc[q][n] = e;
            s += e;
        }
        #pragma unroll
        for (int off = 32; off > 0; off >>= 1) s += __shfl_xor(s, off);

        const float inv = 1.f / s;
        float* out = probs + (size_t)bp * N_;
        for (int n = lane; n < N_; n += 64) out[n] = sc[q][n] * inv;
    }
}

// ---------------------------------------------------------------------------
extern "C" void kernel_launch(void* const* d_in, const int* in_sizes, int n_in,
                              void* d_out, int out_size, void* d_ws, size_t ws_size,
                              hipStream_t stream)
{
    const float* eln      = (const float*)d_in[0];
    const float* load_    = (const float*)d_in[1];
    const float* time_    = (const float*)d_in[2];
    const float* cur_dist = (const float*)d_in[3];
    const float* ninf     = (const float*)d_in[4];
    const float* noise    = (const float*)d_in[5];
    const float* en       = (const float*)d_in[6];
    const float* Wq       = (const float*)d_in[7];
    const float* Wk       = (const float*)d_in[8];
    const float* Wv       = (const float*)d_in[9];
    const float* Wc       = (const float*)d_in[10];
    const float* bc       = (const float*)d_in[11];
    float* probs = (float*)d_out;

    float* K2    = (float*)d_ws;                         // B*H*N*16
    float* V2    = K2 + (size_t)B_ * HEAD_ * N_ * 16;    // B*H*N*16
    float* Q     = V2 + (size_t)B_ * HEAD_ * N_ * 16;    // B*P*128
    float* out_g = Q  + (size_t)B_ * P_ * 128;           // B*P*128

    kv_proj<<<(B_ * N_) / 32, 256, 0, stream>>>(en, Wk, Wv, K2, V2);
    q_proj<<<(B_ * P_) / 8, 128, 0, stream>>>(eln, load_, time_, Wq, Q);
    attn_heads<<<B_ * HEAD_ * (P_ / QT), 256, 0, stream>>>(K2, V2, Q, ninf, out_g);
    ptr_epilogue<<<(B_ * P_) / QT, 256, 0, stream>>>(out_g, en, Wc, bc,
                                                     cur_dist, ninf, noise, probs);
}